// Round 7
// baseline (253.503 us; speedup 1.0000x reference)
//
#include <hip/hip_runtime.h>
#include <hip/hip_bf16.h>

// MultiAgentSEPSNetwork: A=8 agents, E=4096, O=256, H1=H2=1024, H3=512, S=4.
// M = A*E = 32768 rows. Only the seps_idx-selected net per agent is computed.
//
// R15: R14 = 70us L2 / MfmaUtil 39%. Residual = per-phase block-wide
// lockstep: 4 barriers/tile x 8 waves at 2 waves/SIMD (1 block/CU) means
// every window pays skew+drain to the slowest wave. Barrier-necessity
// audit: within a tile all ds_reads hit the LIVE buffer and all DMAs hit
// the DEAD buffer -> intra-tile barriers enforce nothing. Required syncs:
//   RAW  (DMA->read buf[T])    : vmcnt(0)+barrier at end of T-1   [kept]
//   WAR  (T-1 reads -> T DMAs) : reads consumed by MFMAs before the
//         T-1-end barrier (SB0 pins them above it); STAGEs issue after  [ok]
//   WAW  (STAGE T+1 vs T-1)    : drained at end of T-2             [ok]
// => ONE barrier per tile. Waves slip up to a tile; LDS and MFMA pipes
// overlap across waves; register WAR on af/bf orders each wave's pipeline
// (LDA(1) overwrites af consumed by MFMA(0,*)). The single barrier is
// bracketed by sched_barrier(0) on BOTH sides: SB0-before stops MFMA
// sinking (WAR keystone), SB0-after stops next-tile ds_read hoisting
// above the barrier (RAW: other waves' DMAs not yet drained).
// Kept (verified): 256x256, BK=64, dbuf 2x64KB, staging 4+4 early in tile,
// zero-conflict chunk^(l16&7) swizzle, XCD grid swizzle, setprio clusters,
// LDS-transpose epilogue.

typedef unsigned short u16;
typedef __bf16 bf16x8 __attribute__((ext_vector_type(8)));
typedef float floatx4 __attribute__((ext_vector_type(4)));

__device__ __forceinline__ u16 f2bf(float f) {
    union { float f; unsigned int u; } v; v.f = f;
    unsigned int u = v.u;
    return (u16)((u + 0x7FFFu + ((u >> 16) & 1u)) >> 16);
}

// global -> LDS direct DMA, 16 B/lane. LDS dest = wave-uniform base + lane*16.
__device__ __forceinline__ void load16(const void* g, void* l) {
    __builtin_amdgcn_global_load_lds(
        (const __attribute__((address_space(1))) void*)(unsigned long long)g,
        (__attribute__((address_space(3))) void*)(unsigned int)(unsigned long long)l,
        16, 0, 0);
}

// ---------------- fused prep: x->bf16 + 3 weight transposes ----------------
__global__ __launch_bounds__(256) void prep(
    const float* __restrict__ x, u16* __restrict__ xb,
    const float* __restrict__ W1, u16* __restrict__ w1t,
    const float* __restrict__ W2, u16* __restrict__ w2t,
    const float* __restrict__ W3, u16* __restrict__ w3t) {
    __shared__ float tile[32][33];
    int b = blockIdx.x;
    const int tid = threadIdx.x;
    if (b < 8192) {
        int i = (b * 256 + tid) * 4;
        float4 v = *(const float4*)(x + i);
        ushort4 o;
        o.x = f2bf(v.x); o.y = f2bf(v.y); o.z = f2bf(v.z); o.w = f2bf(v.w);
        *(ushort4*)(xb + i) = o;
        return;
    }
    b -= 8192;
    const float* src; u16* dst; int K, N, n0, k0, s;
    if (b < 1024) {                     // W1 [4][256][1024] -> [4][1024][256]
        s = b >> 8; int r = b & 255;
        K = 256; N = 1024; n0 = (r & 31) * 32; k0 = (r >> 5) * 32;
        src = W1; dst = w1t;
    } else if (b < 5120) {              // W2 [4][1024][1024] -> same^T
        b -= 1024; s = b >> 10; int r = b & 1023;
        K = 1024; N = 1024; n0 = (r & 31) * 32; k0 = (r >> 5) * 32;
        src = W2; dst = w2t;
    } else {                            // W3 [4][1024][512] -> [4][512][1024]
        b -= 5120; s = b >> 9; int r = b & 511;
        K = 1024; N = 512; n0 = (r & 15) * 32; k0 = (r >> 4) * 32;
        src = W3; dst = w3t;
    }
    src += (size_t)s * K * N;
    dst += (size_t)s * N * K;
    const int tx = tid & 31, ty = tid >> 5;
#pragma unroll
    for (int j = 0; j < 32; j += 8)
        tile[ty + j][tx] = src[(size_t)(k0 + ty + j) * N + (n0 + tx)];
    __syncthreads();
#pragma unroll
    for (int j = 0; j < 32; j += 8)
        dst[(size_t)(n0 + ty + j) * K + (k0 + tx)] = f2bf(tile[tx][ty + j]);
}

// ---- fragment-load / MFMA building blocks (compile-time H/V) ----
#define LDA(H)                                                                 \
    {                                                                          \
        _Pragma("unroll") for (int i = 0; i < 4; ++i)                          \
            _Pragma("unroll") for (int kk = 0; kk < 2; ++kk)                   \
                af[i][kk] = *(const bf16x8*)&buf[arow0 + ((H) << 12) +         \
                                                 (i << 10) + cs[kk]];          \
    }

#define LDB(V, BF)                                                             \
    {                                                                          \
        _Pragma("unroll") for (int j = 0; j < 2; ++j)                          \
            _Pragma("unroll") for (int kk = 0; kk < 2; ++kk)                   \
                BF[j][kk] = *(const bf16x8*)&buf[16384 + brow0 +               \
                                                 ((((V) << 1) + j) << 10) +    \
                                                 cs[kk]];                      \
    }

#define MFMA16(H, V, BF)                                                       \
    {                                                                          \
        __builtin_amdgcn_s_setprio(1);                                         \
        _Pragma("unroll") for (int i = 0; i < 4; ++i)                          \
            _Pragma("unroll") for (int j = 0; j < 2; ++j)                      \
                _Pragma("unroll") for (int kk = 0; kk < 2; ++kk)               \
                    acc[((H) << 2) + i][((V) << 1) + j] =                      \
                        __builtin_amdgcn_mfma_f32_16x16x32_bf16(               \
                            af[i][kk], BF[j][kk],                              \
                            acc[((H) << 2) + i][((V) << 1) + j], 0, 0, 0);     \
        __builtin_amdgcn_s_setprio(0);                                         \
    }

// ------------- grouped GEMM: 256x256, BK=64, dbuf, 1 barrier/tile -------------
// C[m,n] = act(A[M,K] @ Wt[s][N,K]^T + bias[s][N]);  s = seps[agent(m)]
// 512 thr = 8 waves (2M x 4N); per-wave C = 128x64 (acc 8x4); 16x16x32 MFMA.
// LDS: 2 buffers x {A 256x64 | B 256x64} bf16 = 2 x 64KB. 128B rows,
// chunk ^ (l16&7) swizzle (0 conflicts, verified R10/R12/R13/R14).
template <int K, int N, bool RELU, bool OUT_BF16>
__global__ __launch_bounds__(512, 2) void gemm_mlp(
    const u16* __restrict__ Amat, const u16* __restrict__ Wt,
    const float* __restrict__ bias, const int* __restrict__ seps,
    void* __restrict__ outp) {
    constexpr int BK = 64;
    constexpr int NT = K / BK;
    constexpr int NNB = N / 256;               // n-blocks per m-stripe (4 or 2)
    constexpr int LNB = (NNB == 4) ? 2 : 1;
    extern __shared__ u16 lds[];               // 128 KB dynamic

    const int tid = threadIdx.x;
    const int wave = tid >> 6, lane = tid & 63;
    const int wm = wave >> 2, wn = wave & 3;
    const int quad = lane >> 4, l16 = lane & 15;

    // XCD swizzle: block i -> XCD i%8; all NNB n-blocks of one m-stripe are
    // dispatch-adjacent and share i%8 -> one XCD's L2 holds the A-stripe.
    const int bidx = blockIdx.x;
    const int t = bidx >> 3;
    const int mb = (t >> LNB) * 8 + (bidx & 7);
    const int nb = t & (NNB - 1);
    const int m0 = mb * 256, n0 = nb * 256;

    const int s = seps[m0 >> 12];              // 4096 rows per agent
    const u16* Ab = Amat + (size_t)m0 * K;
    const u16* Bb = Wt + ((size_t)s * N + n0) * K;

    // staging: half-tile (128 rows x 64 k) per STAGEH = 2 load16/thread.
    // Wave w, lane L: row = w*8 + (L>>3), LDS slot L&7 <- global chunk
    // (L&7)^(L>>3)  => LDS[r][c] = G[r][c ^ (r&7)]  (involution on read).
    const int srow = (wave << 3) + (lane >> 3);
    const int sch = ((lane & 7) ^ (lane >> 3)) << 3;
    const u16* gA = Ab + (size_t)srow * K + sch;
    const u16* gB = Bb + (size_t)srow * K + sch;
    const unsigned lsw = (unsigned)(wave << 9);   // wave*8 rows * 64 u16

    // ht: 0=A rows[0,128) 1=A rows[128,256) 2=B rows[0,128) 3=B rows[128,256)
    auto STAGEH = [&](int T1, int ht) {
        u16* dbuf = &lds[(T1 & 1) << 15];      // 32768 u16 per buffer
        const int k0 = T1 * BK;
        const u16* g = (ht & 2) ? gB : gA;
        const int r0 = (ht & 1) << 7;
#pragma unroll
        for (int q = 0; q < 2; ++q)
            load16(g + (size_t)(r0 + (q << 6)) * K + k0,
                   dbuf + ht * 8192 + (q << 12) + lsw);
    };

    // fragment read bases (u16 index): row stride 64 u16 = 128 B.
    // de-swizzle slot = chunk ^ (l16&7)  (row&7 == l16&7, rows step by 16).
    const int arow0 = ((wm << 7) + l16) << 6;
    const int brow0 = ((wn << 6) + l16) << 6;
    int cs[2];
    cs[0] = ((quad ^ (l16 & 7)) << 3);
    cs[1] = (((4 + quad) ^ (l16 & 7)) << 3);

    floatx4 acc[8][4];
#pragma unroll
    for (int i = 0; i < 8; ++i)
#pragma unroll
        for (int j = 0; j < 4; ++j) acc[i][j] = (floatx4){0.f, 0.f, 0.f, 0.f};

    // prologue: stage tile 0 fully, drain, publish.
    STAGEH(0, 0); STAGEH(0, 2); STAGEH(0, 3); STAGEH(0, 1);
    asm volatile("s_waitcnt vmcnt(0)" ::: "memory");
    __builtin_amdgcn_s_barrier();
    __builtin_amdgcn_sched_barrier(0);

    bf16x8 af[4][2], bf0[2][2], bf1[2][2];

#pragma unroll 1
    for (int T = 0; T < NT; ++T) {
        const u16* buf = &lds[(T & 1) << 15];
        const bool more = (T + 1 < NT);

        // tile body: no internal barriers. Register WAR (LDA(1) overwrites
        // af consumed by MFMA(0,*)) orders each wave's pipeline; waves slip
        // freely so one wave's ds_reads overlap another's MFMA cluster.
        LDA(0); LDB(0, bf0);
        if (more) { STAGEH(T + 1, 0); STAGEH(T + 1, 2); }
        MFMA16(0, 0, bf0);
        LDB(1, bf1);
        if (more) { STAGEH(T + 1, 3); STAGEH(T + 1, 1); }
        MFMA16(0, 1, bf1);
        LDA(1);
        MFMA16(1, 1, bf1);
        MFMA16(1, 0, bf0);

        // single sync point per tile: drain this tile's DMAs (issued early
        // in this body, ~full tile of cover), pin MFMAs above (WAR), then
        // barrier; SB0-after stops next tile's reads hoisting above (RAW).
        asm volatile("s_waitcnt vmcnt(0)" ::: "memory");
        __builtin_amdgcn_sched_barrier(0);
        __builtin_amdgcn_s_barrier();
        __builtin_amdgcn_sched_barrier(0);
    }
    __syncthreads();   // all LDS traffic done before epilogue reuse

    // ---- epilogue: 8 mf-phases, LDS transpose, coalesced stores ----
    float* eps = (float*)lds;                  // [32][268] f32 per phase
    constexpr int EW = 268;
    float bv[4];
#pragma unroll
    for (int nf = 0; nf < 4; ++nf)
        bv[nf] = bias[s * N + n0 + (wn << 6) + (nf << 4) + l16];

    const int rL = tid & 63;                   // float4 column slot
    const int rw = tid >> 6;                   // row base

#pragma unroll
    for (int mf = 0; mf < 8; ++mf) {
#pragma unroll
        for (int nf = 0; nf < 4; ++nf)
#pragma unroll
            for (int r = 0; r < 4; ++r) {
                float v = acc[mf][nf][r] + bv[nf];
                if (RELU) v = fmaxf(v, 0.0f);
                eps[((wm << 4) + (quad << 2) + r) * EW + (wn << 6) + (nf << 4) + l16] = v;
            }
        __syncthreads();
#pragma unroll
        for (int j = 0; j < 4; ++j) {
            const int er = rw + (j << 3);      // 0..31
            const int grow = m0 + ((er >> 4) << 7) + (mf << 4) + (er & 15);
            const float4 v = *(const float4*)&eps[er * EW + (rL << 2)];
            if (OUT_BF16) {
                ushort4 o;
                o.x = f2bf(v.x); o.y = f2bf(v.y); o.z = f2bf(v.z); o.w = f2bf(v.w);
                *(ushort4*)((u16*)outp + (size_t)grow * N + n0 + (rL << 2)) = o;
            } else {
                *(float4*)((float*)outp + (size_t)grow * N + n0 + (rL << 2)) = v;
            }
        }
        __syncthreads();
    }
}

extern "C" void kernel_launch(void* const* d_in, const int* in_sizes, int n_in,
                              void* d_out, int out_size, void* d_ws, size_t ws_size,
                              hipStream_t stream) {
    const float* x  = (const float*)d_in[0];
    const float* W1 = (const float*)d_in[1];
    const float* b1 = (const float*)d_in[2];
    const float* W2 = (const float*)d_in[3];
    const float* b2 = (const float*)d_in[4];
    const float* W3 = (const float*)d_in[5];
    const float* b3 = (const float*)d_in[6];
    const int* seps = (const int*)d_in[7];

    char* ws = (char*)d_ws;
    u16* w1t = (u16*)(ws);                    //  2 MB: [4][1024][256]
    u16* w2t = (u16*)(ws + (2ull << 20));     //  8 MB: [4][1024][1024]
    u16* w3t = (u16*)(ws + (10ull << 20));    //  4 MB: [4][512][1024]
    u16* xb  = (u16*)(ws + (14ull << 20));    // 16 MB: [32768][256]
    u16* h1  = (u16*)(ws + (30ull << 20));    // 64 MB: [32768][1024]
    u16* h2  = (u16*)(ws + (94ull << 20));    // 64 MB: [32768][1024]

    // 128 KB dynamic LDS opt-in (host-side, once).
    static int attr_once = []() {
        auto k1 = gemm_mlp<256, 1024, true, true>;
        auto k2 = gemm_mlp<1024, 1024, true, true>;
        auto k3 = gemm_mlp<1024, 512, false, false>;
        hipFuncSetAttribute(reinterpret_cast<const void*>(k1),
                            hipFuncAttributeMaxDynamicSharedMemorySize, 131072);
        hipFuncSetAttribute(reinterpret_cast<const void*>(k2),
                            hipFuncAttributeMaxDynamicSharedMemorySize, 131072);
        hipFuncSetAttribute(reinterpret_cast<const void*>(k3),
                            hipFuncAttributeMaxDynamicSharedMemorySize, 131072);
        return 0;
    }();
    (void)attr_once;

    prep<<<15360, 256, 0, stream>>>(x, xb, W1, w1t, W2, w2t, W3, w3t);

    // L1: [32768,256]@[256,1024]^T +b1, relu -> h1 (bf16)
    gemm_mlp<256, 1024, true, true><<<512, 512, 131072, stream>>>(xb, w1t, b1, seps, h1);
    // L2: [32768,1024]@[1024,1024]^T +b2, relu -> h2 (bf16)
    gemm_mlp<1024, 1024, true, true><<<512, 512, 131072, stream>>>(h1, w2t, b2, seps, h2);
    // L3: [32768,1024]@[1024,512]^T +b3 -> out (f32)
    gemm_mlp<1024, 512, false, false><<<256, 512, 131072, stream>>>(h2, w3t, b3, seps, d_out);
}